// Round 1
// baseline (229.637 us; speedup 1.0000x reference)
//
#include <hip/hip_runtime.h>

// GridSpatialIntegral: out[:,0] = cumsum_x(in[:,0]); out[:,1] = cumsum_y(in[:,1])
// Shapes: [B=64, C=2, 512, 512] fp32. Memory-bound: 128 MiB in + 128 MiB out.

#define BATCH 64
#define W 512   // WY == WX == 512

// Grid layout:
//   blocks [0, 2048):    channel 0 — 16 rows/block, one row per wave (64*512/16 = 2048)
//   blocks [2048, 2560): channel 1 — 64 columns/block, 16 y-segments of 32 (64*8 = 512)
// Block: 1024 threads (16 waves).

__global__ __launch_bounds__(1024)
void gsi_kernel(const float* __restrict__ in, float* __restrict__ out) {
    __shared__ float seg_sums[16][64];   // channel-1 path only
    const int tid = threadIdx.x;

    if (blockIdx.x < 2048) {
        // ---------------- channel 0: inclusive scan along contiguous x ----------------
        const int wave = tid >> 6;            // 0..15
        const int lane = tid & 63;
        const int row  = (blockIdx.x << 4) + wave;   // 0..32767
        const int b    = row >> 9;
        const int y    = row & 511;
        const size_t base = (size_t)b * (2 * W * W) + (size_t)y * W;   // channel 0

        const float4* ip = (const float4*)(in + base);
        float4*       op = (float4*)(out + base);

        float4 v0 = ip[lane * 2];
        float4 v1 = ip[lane * 2 + 1];

        float e0 = v0.x;
        float e1 = e0 + v0.y;
        float e2 = e1 + v0.z;
        float e3 = e2 + v0.w;
        float e4 = e3 + v1.x;
        float e5 = e4 + v1.y;
        float e6 = e5 + v1.z;
        float e7 = e6 + v1.w;

        // wave-level inclusive scan of per-lane totals (64 lanes)
        float s = e7;
        #pragma unroll
        for (int off = 1; off < 64; off <<= 1) {
            float t = __shfl_up(s, off, 64);
            if (lane >= off) s += t;
        }
        const float offset = s - e7;   // exclusive prefix for this lane

        v0 = make_float4(e0 + offset, e1 + offset, e2 + offset, e3 + offset);
        v1 = make_float4(e4 + offset, e5 + offset, e6 + offset, e7 + offset);
        op[lane * 2]     = v0;
        op[lane * 2 + 1] = v1;
    } else {
        // ---------------- channel 1: inclusive scan along strided y ----------------
        const int bi = blockIdx.x - 2048;     // 0..511
        const int b  = bi >> 3;
        const int x0 = (bi & 7) << 6;         // 64-column tile
        const int tx = tid & 63;              // column within tile
        const int ty = tid >> 6;              // 0..15, y-segment of 32 rows

        const size_t base = (size_t)b * (2 * W * W) + (size_t)(W * W)  // channel 1
                          + (size_t)x0 + (size_t)tx;
        const float* ip = in  + base + (size_t)(ty * 32) * W;
        float*       op = out + base + (size_t)(ty * 32) * W;

        // Load the 32-row segment into registers; 32 independent loads in flight.
        float d[32];
        float sum = 0.f;
        #pragma unroll
        for (int k = 0; k < 32; ++k) {
            d[k] = ip[(size_t)k * W];
            sum += d[k];
        }

        seg_sums[ty][tx] = sum;
        __syncthreads();

        float offset = 0.f;
        for (int j = 0; j < ty; ++j) offset += seg_sums[j][tx];

        float acc = offset;
        #pragma unroll
        for (int k = 0; k < 32; ++k) {
            acc += d[k];
            op[(size_t)k * W] = acc;
        }
    }
}

extern "C" void kernel_launch(void* const* d_in, const int* in_sizes, int n_in,
                              void* d_out, int out_size, void* d_ws, size_t ws_size,
                              hipStream_t stream) {
    const float* in  = (const float*)d_in[0];
    float*       out = (float*)d_out;
    (void)in_sizes; (void)n_in; (void)out_size; (void)d_ws; (void)ws_size;
    gsi_kernel<<<dim3(2048 + 512), dim3(1024), 0, stream>>>(in, out);
}